// Round 3
// baseline (29775.427 us; speedup 1.0000x reference)
//
#include <hip/hip_runtime.h>

// ---------------- problem constants ----------------
#define BB_ 32      // batch
#define SS_ 256     // src len
#define TD_ 63      // decoder steps
#define EE_ 128     // embed
#define HH_ 256     // enc hidden per dir
#define VV_ 32000

__device__ __forceinline__ float sigf(float x){ return 1.0f/(1.0f+__expf(-x)); }
__device__ __forceinline__ float tanhf_fast(float x){ return 1.0f - 2.0f/(__expf(2.0f*x)+1.0f); }

__device__ __forceinline__ unsigned short f2bf(float f){
  unsigned u = __float_as_uint(f);
  u += 0x7fff + ((u >> 16) & 1);
  return (unsigned short)(u >> 16);
}

typedef __attribute__((ext_vector_type(8))) short short8v;
typedef __attribute__((ext_vector_type(8))) unsigned short ushort8v;
typedef __attribute__((ext_vector_type(4))) float f32x4;

// ---------------- d_out scratch layout (float offsets) ----------------
#define OFF_Z        0u           // 8192 x 2048
#define OFF_Y0       16777216u    // 8192 x 512
#define OFF_Y1       20971520u    // 8192 x 512
#define OFF_ZPRE     25165824u    // 2016 x 2048
#define OFF_H1ALL    29294592u    // 2016 x 512
#define OFF_SRCE     30326784u    // 8192 x 128
#define OFF_TGTE     31375360u    // 2016 x 128
#define OFF_EPROJ    31633408u    // 8192 x 256
#define OFF_WBF0     33730560u    // 2x1024x128 u32 (enc Whh l0 packed bf16)
#define OFF_WBF1     34254848u    // 2x1024x128 u32
#define OFF_DTIH0    34779136u    // 128 x 2048 x 4
#define OFF_DTHH0    35827712u
#define OFF_DTIH1    36876288u
#define OFF_DTHH1    37924864u
#define OFF_AT       38973440u    // 128 x 256 x 4 (W1_dec transposed)
#define OFF_E0H0     39104512u    // final states
#define OFF_E0C      39137280u
#define OFF_E1H0     39153664u
#define OFF_E1C      39186432u
#define OFF_DH0A     39202816u
#define OFF_DH0B     39219200u
#define OFF_DC0      39235584u
#define OFF_DH1A     39251968u
#define OFF_DH1B     39268352u
#define OFF_DC1      39284736u
#define OFF_CTX      39301120u    // 32 x 512
#define OFF_HA       39317504u    // enc h dbuf A (64 x 256)
#define OFF_HB       39333888u    // enc h dbuf B
#define OFF_QG       39350272u    // 32 x 256
#define OFF_SCG      39358464u    // 32 x 256
#define OFF_BAR      39366656u    // barrier counters (768 u32)

// ---------------- device barrier (device-scope, sub-grid domain) ----------------
__device__ __forceinline__ void dbar(unsigned* ctr, unsigned target){
  __threadfence();
  __syncthreads();
  if (threadIdx.x == 0){
    atomicAdd(ctr, 1u);
    while (__hip_atomic_load(ctr, __ATOMIC_RELAXED, __HIP_MEMORY_SCOPE_AGENT) < target)
      __builtin_amdgcn_s_sleep(1);
  }
  __syncthreads();
  __threadfence();
}

// ---------------- utility kernels ----------------
__global__ void k_zero(float* __restrict__ p, int n){
  int i = blockIdx.x*256 + threadIdx.x;
  if (i < n) p[i] = 0.f;
}

// pack enc Whh (2,1024,256) f32 -> bf16 pairs [d][col][k2]
__global__ void k_packbf(const float* __restrict__ src, unsigned* __restrict__ dst, int n){
  int i = blockIdx.x*256 + threadIdx.x;
  if (i >= n) return;
  float a = src[i*2], b = src[i*2+1];
  dst[i] = (unsigned)f2bf(a) | ((unsigned)f2bf(b) << 16);
}

__global__ void k_gather(const int* __restrict__ src, const int* __restrict__ tgt,
                         const float* __restrict__ emb,
                         float* __restrict__ src_e, float* __restrict__ tgt_e){
  int idx = blockIdx.x*256 + threadIdx.x;
  const int total = (8192 + 2016) * 32;
  if (idx >= total) return;
  int row = idx >> 5, j = idx & 31;
  int tok; float* dst;
  if (row < 8192){
    int s = row >> 5, b = row & 31;
    tok = src[b*SS_ + s];
    dst = src_e + (size_t)row*EE_;
  } else {
    int r2 = row - 8192;
    int t = r2 >> 5, b = r2 & 31;
    tok = tgt[b*64 + t];
    dst = tgt_e + (size_t)r2*EE_;
  }
  float4 v = *(const float4*)(emb + (size_t)tok*EE_ + j*4);
  *(float4*)(dst + j*4) = v;
}

// transpose W (C rows x Kd cols, row stride ldb, col offset off) into
// WT[(k/4)*C + c]*4 + (k%4)  (k-major float4 interleave)
__global__ __launch_bounds__(256) void k_transpose(
    const float* __restrict__ src, float* __restrict__ dst,
    int C, int Kd, int ldb, int off){
  __shared__ float tile[64][68];
  int c0 = blockIdx.x*64, k0 = blockIdx.y*64;
  int tid = threadIdx.x;
  for (int idx = tid; idx < 1024; idx += 256){
    int r = idx >> 4, j4 = idx & 15;
    float4 v = *(const float4*)(src + (size_t)(c0+r)*ldb + off + k0 + j4*4);
    tile[r][j4*4+0]=v.x; tile[r][j4*4+1]=v.y; tile[r][j4*4+2]=v.z; tile[r][j4*4+3]=v.w;
  }
  __syncthreads();
  for (int idx = tid; idx < 1024; idx += 256){
    int k4l = idx >> 6, cl = idx & 63;
    float4 v = make_float4(tile[cl][k4l*4+0], tile[cl][k4l*4+1],
                           tile[cl][k4l*4+2], tile[cl][k4l*4+3]);
    *(float4*)(dst + ((size_t)(k0/4 + k4l)*C + c0 + cl)*4) = v;
  }
}

// ---------------- bf16 MFMA GEMM ----------------
__global__ __launch_bounds__(256) void k_mgemm(
    const float* __restrict__ A, const float* __restrict__ Bm,
    const float* __restrict__ bias, float* __restrict__ C,
    int M, int N, int K, int ldb, int boff, int flags){
  __shared__ unsigned short As[128*72];
  __shared__ unsigned short Bs[128*72];
  int tid = threadIdx.x;
  int m0 = blockIdx.x*128, n0 = blockIdx.y*128;
  int l = tid & 63, w = tid >> 6;
  int wr = w >> 1, wc = w & 1;
  int lr = l & 15, lk = (l >> 4) * 8;
  f32x4 acc[4][4];
  #pragma unroll
  for (int m=0;m<4;m++)
    #pragma unroll
    for (int n=0;n<4;n++) acc[m][n] = (f32x4){0.f,0.f,0.f,0.f};

  int r = tid >> 1, half = tid & 1;
  bool aval = (m0 + r) < M;
  const float* arow = A + (size_t)(m0 + r)*K + half*32;
  const float* brow = Bm + (size_t)(n0 + r)*ldb + boff + half*32;
  unsigned short* asd = &As[r*72 + half*32];
  unsigned short* bsd = &Bs[r*72 + half*32];

  for (int k0 = 0; k0 < K; k0 += 64){
    #pragma unroll
    for (int j = 0; j < 4; j++){
      float4 x = make_float4(0.f,0.f,0.f,0.f), y = x;
      if (aval){
        x = *(const float4*)(arow + k0 + j*8);
        y = *(const float4*)(arow + k0 + j*8 + 4);
      }
      ushort8v v;
      v[0]=f2bf(x.x); v[1]=f2bf(x.y); v[2]=f2bf(x.z); v[3]=f2bf(x.w);
      v[4]=f2bf(y.x); v[5]=f2bf(y.y); v[6]=f2bf(y.z); v[7]=f2bf(y.w);
      *(ushort8v*)(asd + j*8) = v;
      float4 p = *(const float4*)(brow + k0 + j*8);
      float4 q = *(const float4*)(brow + k0 + j*8 + 4);
      ushort8v u;
      u[0]=f2bf(p.x); u[1]=f2bf(p.y); u[2]=f2bf(p.z); u[3]=f2bf(p.w);
      u[4]=f2bf(q.x); u[5]=f2bf(q.y); u[6]=f2bf(q.z); u[7]=f2bf(q.w);
      *(ushort8v*)(bsd + j*8) = u;
    }
    __syncthreads();
    #pragma unroll
    for (int kk = 0; kk < 2; kk++){
      short8v aF[4], bF[4];
      #pragma unroll
      for (int m = 0; m < 4; m++)
        aF[m] = *(short8v*)&As[(wr*64 + m*16 + lr)*72 + kk*32 + lk];
      #pragma unroll
      for (int n = 0; n < 4; n++)
        bF[n] = *(short8v*)&Bs[(wc*64 + n*16 + lr)*72 + kk*32 + lk];
      #pragma unroll
      for (int m = 0; m < 4; m++)
        #pragma unroll
        for (int n = 0; n < 4; n++)
          acc[m][n] = __builtin_amdgcn_mfma_f32_16x16x32_bf16(aF[m], bF[n], acc[m][n], 0, 0, 0);
    }
    __syncthreads();
  }

  #pragma unroll
  for (int m = 0; m < 4; m++){
    int gr0 = m0 + wr*64 + m*16 + (l >> 4)*4;
    #pragma unroll
    for (int n = 0; n < 4; n++){
      int gc = n0 + wc*64 + n*16 + (l & 15);
      float bv = bias[gc];
      #pragma unroll
      for (int j = 0; j < 4; j++){
        int gr = gr0 + j;
        if (gr >= M) continue;
        float v = acc[m][n][j] + bv;
        if (flags & 1) v = fmaxf(v, 0.f);
        if (flags & 2){
          int t = gr >> 5, b = gr & 31;
          C[((size_t)(b*63 + t))*(size_t)N + gc] = v;
        } else {
          C[(size_t)gr*N + gc] = v;
        }
      }
    }
  }
}

// ---------------- persistent encoder scan (one bi-dir layer) ----------------
// 128 blocks: us(16) x bg(4) x d(2). Domain = (bg,d): 16 blocks.
// Whh slice in LDS as packed bf16. h double-buffered in global, c in registers.
__global__ __launch_bounds__(256) void k_enc_scan(
    const float* __restrict__ Z, const unsigned* __restrict__ Wbf,
    float* __restrict__ y, float* __restrict__ hA, float* __restrict__ hB,
    float* __restrict__ hfin, float* __restrict__ cfin,
    unsigned* __restrict__ bar){
  int blk = blockIdx.x;
  int us = blk & 15, bg = (blk>>4)&3, d = blk>>6;
  unsigned* ctr = bar + (blk>>4)*32;    // domain = bg + 4*d
  int tid = threadIdx.x;
  __shared__ unsigned wl[64][132];
  __shared__ float hs[8][258];
  __shared__ float zred[4][64][9];

  // load weight slice: local col c -> global col (c>>4)*256 + us*16 + (c&15)
  for (int idx = tid; idx < 64*128; idx += 256){
    int c = idx >> 7, k2 = idx & 127;
    int colg = (c>>4)*256 + us*16 + (c&15);
    wl[c][k2] = Wbf[((size_t)d*1024 + colg)*128 + k2];
  }
  // zero my h slice in hA; c in registers (epilogue threads tid<128)
  int u_l = tid & 15, b_l = (tid >> 4) & 7;
  float creg = 0.f;
  if (tid < 128)
    hA[((size_t)d*32 + bg*8 + b_l)*256 + us*16 + u_l] = 0.f;

  unsigned gen = 0;
  dbar(ctr, ++gen * 16u);

  int c_l = tid & 63, kq = tid >> 6;   // dot threads: 64 cols x 4 k-quarters

  for (int i = 0; i < SS_; i++){
    int t = d ? (SS_-1-i) : i;
    float* cur = (i & 1) ? hB : hA;
    float* nxt = (i & 1) ? hA : hB;
    // stage h
    for (int idx = tid; idx < 2048; idx += 256){
      int bb = idx >> 8, k = idx & 255;
      hs[bb][k] = cur[((size_t)d*32 + bg*8 + bb)*256 + k];
    }
    // prefetch Z for epilogue
    float zt0=0.f, zt1=0.f, zt2=0.f, zt3=0.f;
    if (tid < 128){
      const float* zr = Z + ((size_t)t*32 + bg*8 + b_l)*2048 + d*1024 + us*16 + u_l;
      zt0 = zr[0]; zt1 = zr[256]; zt2 = zr[512]; zt3 = zr[768];
    }
    __syncthreads();
    // dots: this thread: col c_l, k in [kq*64, kq*64+64), all 8 batches
    float acc[8];
    #pragma unroll
    for (int bb=0;bb<8;bb++) acc[bb] = 0.f;
    #pragma unroll 8
    for (int j = 0; j < 32; j++){
      int k2 = kq*32 + j;
      unsigned wv = wl[c_l][k2];
      float wlo = __uint_as_float(wv << 16);
      float whi = __uint_as_float(wv & 0xffff0000u);
      #pragma unroll
      for (int bb=0;bb<8;bb++)
        acc[bb] += wlo*hs[bb][2*k2] + whi*hs[bb][2*k2+1];
    }
    __syncthreads();
    #pragma unroll
    for (int bb=0;bb<8;bb++) zred[kq][c_l][bb] = acc[bb];
    __syncthreads();
    if (tid < 128){
      float zg[4];
      #pragma unroll
      for (int g=0;g<4;g++){
        int c = g*16 + u_l;
        zg[g] = zred[0][c][b_l] + zred[1][c][b_l] + zred[2][c][b_l] + zred[3][c][b_l];
      }
      zg[0] += zt0; zg[1] += zt1; zg[2] += zt2; zg[3] += zt3;
      float cn = sigf(zg[1])*creg + sigf(zg[0])*tanhf_fast(zg[2]);
      float hn = sigf(zg[3])*tanhf_fast(cn);
      creg = cn;
      size_t hidx = ((size_t)d*32 + bg*8 + b_l)*256 + us*16 + u_l;
      nxt[hidx] = hn;
      y[((size_t)t*32 + bg*8 + b_l)*512 + d*256 + us*16 + u_l] = hn;
      if (i == SS_-1){ hfin[hidx] = hn; cfin[hidx] = cn; }
    }
    dbar(ctr, ++gen * 16u);
  }
}

// ---------------- persistent decoder scan ----------------
// 256 blocks = bg(4 domains) x j(64). 5 phases per step with domain barriers.
__global__ __launch_bounds__(256) void k_dec_scan(
    const float* __restrict__ aT, const float* __restrict__ eproj,
    const float* __restrict__ aW2, const float* __restrict__ ab2,
    const float* __restrict__ y1, const float* __restrict__ zpre,
    const float* __restrict__ db1,
    const float* __restrict__ dTih0, const float* __restrict__ dThh0,
    const float* __restrict__ dTih1, const float* __restrict__ dThh1,
    float* __restrict__ h0A, float* __restrict__ h0B, float* __restrict__ c0,
    float* __restrict__ h1A, float* __restrict__ h1B, float* __restrict__ c1,
    float* __restrict__ qg, float* __restrict__ scg, float* __restrict__ ctxg,
    float* __restrict__ H1all, unsigned* __restrict__ bar){
  int blk = blockIdx.x;
  int bg = blk >> 6, j = blk & 63;
  unsigned* ctr = bar + bg*32;
  int tid = threadIdx.x;
  __shared__ float sA[8][516];
  __shared__ float sB[8][516];
  __shared__ float sm[520];
  float* sAf = &sA[0][0];
  unsigned gen = 0;

  int b_l = j >> 3, sub = j & 7;       // for attention phases
  int b_att = bg*8 + b_l;

  for (int t = 0; t < TD_; t++){
    const float* h1cur = (t & 1) ? h1B : h1A;
    float*       h1nxt = (t & 1) ? h1A : h1B;
    const float* h0cur = (t & 1) ? h0B : h0A;
    float*       h0nxt = (t & 1) ? h0A : h0B;

    // ---- P1: q slice: q[b][sub*32 .. +32] ----
    {
      for (int k = tid; k < 512; k += 256) sAf[k] = h1cur[(size_t)b_att*512 + k];
      __syncthreads();
      int c32 = tid & 31, kc = tid >> 5;      // 32 cols x 8 k-chunks (16 float4 each)
      int col = sub*32 + c32;
      const float4* w4 = (const float4*)aT;
      const float4* h4 = (const float4*)sAf;
      float a0 = 0.f;
      #pragma unroll 4
      for (int jj = 0; jj < 16; jj++){
        int k4 = kc*16 + jj;
        float4 wv = w4[(size_t)k4*256 + col];
        float4 hv = h4[k4];
        a0 += wv.x*hv.x + wv.y*hv.y + wv.z*hv.z + wv.w*hv.w;
      }
      sm[c32*8 + kc] = a0;
      __syncthreads();
      if (tid < 32){
        float q = 0.f;
        #pragma unroll
        for (int kk=0;kk<8;kk++) q += sm[tid*8 + kk];
        qg[(size_t)b_att*256 + sub*32 + tid] = q;
      }
    }
    dbar(ctr, ++gen * 64u);

    // ---- P2: scores slice: sc[b][sub*32 .. +32] ----
    {
      sm[tid] = qg[(size_t)b_att*256 + tid];
      sm[256 + tid] = aW2[tid];
      __syncthreads();
      int sl = tid >> 3, hc = tid & 7;
      int s = sub*32 + sl;
      const float4* ep = (const float4*)(eproj + ((size_t)s*32 + b_att)*256 + hc*32);
      const float4* q4 = (const float4*)(sm + hc*32);
      const float4* w4 = (const float4*)(sm + 256 + hc*32);
      float acc = 0.f;
      #pragma unroll
      for (int k=0;k<8;k++){
        float4 e = ep[k], qq = q4[k], ww = w4[k];
        acc += tanhf_fast(e.x+qq.x)*ww.x + tanhf_fast(e.y+qq.y)*ww.y
             + tanhf_fast(e.z+qq.z)*ww.z + tanhf_fast(e.w+qq.w)*ww.w;
      }
      sAf[sl*9 + hc] = acc;
      __syncthreads();
      if (hc == 0){
        float r = 0.f;
        #pragma unroll
        for (int kk=0;kk<8;kk++) r += sAf[sl*9 + kk];
        scg[(size_t)b_att*256 + s] = r + ab2[0];
      }
    }
    dbar(ctr, ++gen * 64u);

    // ---- P3: softmax + ctx slice: ctx[b][sub*64 .. +64] ----
    {
      float scv = scg[(size_t)b_att*256 + tid];
      sAf[tid] = scv;
      __syncthreads();
      for (int off=128; off; off >>= 1){
        if (tid < off) sAf[tid] = fmaxf(sAf[tid], sAf[tid+off]);
        __syncthreads();
      }
      float mx = sAf[0];
      __syncthreads();
      float e = __expf(scv - mx);
      sm[tid] = e;
      sAf[tid] = e;
      __syncthreads();
      for (int off=128; off; off >>= 1){
        if (tid < off) sAf[tid] += sAf[tid+off];
        __syncthreads();
      }
      float inv = 1.0f / sAf[0];
      __syncthreads();
      int dd = tid & 63, sq = tid >> 6;
      float acc = 0.f;
      const float* yb = y1 + (size_t)b_att*512 + sub*64 + dd;
      #pragma unroll 4
      for (int ss=0; ss<64; ss++){
        int s = sq*64 + ss;
        acc += sm[s] * yb[(size_t)s*32*512];
      }
      sAf[dd*5 + sq] = acc;
      __syncthreads();
      if (sq == 0){
        float r = sAf[dd*5] + sAf[dd*5+1] + sAf[dd*5+2] + sAf[dd*5+3];
        ctxg[(size_t)b_att*512 + sub*64 + dd] = r * inv;
      }
    }
    dbar(ctr, ++gen * 64u);

    // ---- P4: lstm cell 0 (j = col-slice cs) ----
    {
      int cs = j;
      for (int idx = tid; idx < 4096; idx += 256){
        int bb = idx >> 9, k = idx & 511;
        int b = bg*8 + bb;
        sA[bb][k] = ctxg[(size_t)b*512 + k];
        sB[bb][k] = h0cur[(size_t)b*512 + k];
      }
      __syncthreads();
      int bb = tid >> 5, cl = tid & 31;
      int gate = cl >> 3, ul = cl & 7;
      int col = gate*512 + cs*8 + ul;
      const float4* w1 = (const float4*)dTih0;
      const float4* w2 = (const float4*)dThh0;
      const float4* p1 = (const float4*)sA[bb];
      const float4* p2 = (const float4*)sB[bb];
      float a = 0.f;
      #pragma unroll 4
      for (int k4=0; k4<128; k4++){
        float4 x = p1[k4], h = p2[k4];
        float4 wa = w1[(size_t)k4*2048 + col];
        float4 va = w2[(size_t)k4*2048 + col];
        a += wa.x*x.x + wa.y*x.y + wa.z*x.z + wa.w*x.w
           + va.x*h.x + va.y*h.y + va.z*h.z + va.w*h.w;
      }
      int b = bg*8 + bb;
      a += zpre[((size_t)t*32 + b)*2048 + col];
      sm[cl*8 + bb] = a;
      __syncthreads();
      if (tid < 64){
        int ul2 = tid & 7, b2 = tid >> 3;
        float zi = sm[(0*8+ul2)*8 + b2], zf = sm[(1*8+ul2)*8 + b2];
        float zgg = sm[(2*8+ul2)*8 + b2], zo = sm[(3*8+ul2)*8 + b2];
        int b3 = bg*8 + b2;
        size_t ci = (size_t)b3*512 + cs*8 + ul2;
        float cn = sigf(zf)*c0[ci] + sigf(zi)*tanhf_fast(zgg);
        float hn = sigf(zo)*tanhf_fast(cn);
        c0[ci] = cn; h0nxt[ci] = hn;
      }
      __syncthreads();
    }
    dbar(ctr, ++gen * 64u);

    // ---- P5: lstm cell 1 ----
    {
      int cs = j;
      for (int idx = tid; idx < 4096; idx += 256){
        int bb = idx >> 9, k = idx & 511;
        int b = bg*8 + bb;
        sA[bb][k] = h0nxt[(size_t)b*512 + k];
        sB[bb][k] = h1cur[(size_t)b*512 + k];
      }
      __syncthreads();
      int bb = tid >> 5, cl = tid & 31;
      int gate = cl >> 3, ul = cl & 7;
      int col = gate*512 + cs*8 + ul;
      const float4* w1 = (const float4*)dTih1;
      const float4* w2 = (const float4*)dThh1;
      const float4* p1 = (const float4*)sA[bb];
      const float4* p2 = (const float4*)sB[bb];
      float a = 0.f;
      #pragma unroll 4
      for (int k4=0; k4<128; k4++){
        float4 x = p1[k4], h = p2[k4];
        float4 wa = w1[(size_t)k4*2048 + col];
        float4 va = w2[(size_t)k4*2048 + col];
        a += wa.x*x.x + wa.y*x.y + wa.z*x.z + wa.w*x.w
           + va.x*h.x + va.y*h.y + va.z*h.z + va.w*h.w;
      }
      a += db1[col];
      sm[cl*8 + bb] = a;
      __syncthreads();
      if (tid < 64){
        int ul2 = tid & 7, b2 = tid >> 3;
        float zi = sm[(0*8+ul2)*8 + b2], zf = sm[(1*8+ul2)*8 + b2];
        float zgg = sm[(2*8+ul2)*8 + b2], zo = sm[(3*8+ul2)*8 + b2];
        int b3 = bg*8 + b2;
        size_t ci = (size_t)b3*512 + cs*8 + ul2;
        float cn = sigf(zf)*c1[ci] + sigf(zi)*tanhf_fast(zgg);
        float hn = sigf(zo)*tanhf_fast(cn);
        c1[ci] = cn; h1nxt[ci] = hn;
        H1all[((size_t)t*32 + b3)*512 + cs*8 + ul2] = hn;
      }
      __syncthreads();
    }
    if (t < TD_-1) dbar(ctr, ++gen * 64u);
    else { ++gen; }
  }
}

// decoder init
__global__ void k_dec_init(
    const float* __restrict__ eh0, const float* __restrict__ ec0,
    const float* __restrict__ eh1, const float* __restrict__ ec1,
    float* __restrict__ h0, float* __restrict__ c0,
    float* __restrict__ h1, float* __restrict__ c1){
  int idx = blockIdx.x*256 + threadIdx.x;
  if (idx >= BB_*512) return;
  int b = idx >> 9, u = idx & 511;
  int d = u >> 8, uu = u & 255;
  size_t s = ((size_t)d*BB_ + b)*256 + uu;
  h0[idx] = eh0[s]; c0[idx] = ec0[s];
  h1[idx] = eh1[s]; c1[idx] = ec1[s];
}

// ---------------- host launch ----------------
extern "C" void kernel_launch(void* const* d_in, const int* in_sizes, int n_in,
                              void* d_out, int out_size, void* d_ws, size_t ws_size,
                              hipStream_t stream){
  (void)in_sizes; (void)n_in; (void)out_size; (void)ws_size;
  const int*   src   = (const int*)d_in[0];
  const int*   tgt   = (const int*)d_in[1];
  const float* emb   = (const float*)d_in[2];
  const float* eWih0 = (const float*)d_in[3];
  const float* eWhh0 = (const float*)d_in[4];
  const float* eb0   = (const float*)d_in[5];
  const float* eWih1 = (const float*)d_in[6];
  const float* eWhh1 = (const float*)d_in[7];
  const float* eb1   = (const float*)d_in[8];
  const float* dWih0 = (const float*)d_in[9];
  const float* dWhh0 = (const float*)d_in[10];
  const float* db0   = (const float*)d_in[11];
  const float* dWih1 = (const float*)d_in[12];
  const float* dWhh1 = (const float*)d_in[13];
  const float* db1   = (const float*)d_in[14];
  const float* aW1   = (const float*)d_in[15];
  const float* ab1   = (const float*)d_in[16];
  const float* aW2   = (const float*)d_in[17];
  const float* ab2   = (const float*)d_in[18];
  const float* oW1   = (const float*)d_in[19];
  const float* ob1   = (const float*)d_in[20];
  const float* oW2   = (const float*)d_in[21];
  const float* ob2   = (const float*)d_in[22];

  float* F = (float*)d_out;
  float* Z     = F + OFF_Z;
  float* y0    = F + OFF_Y0;
  float* y1    = F + OFF_Y1;
  float* zpre  = F + OFF_ZPRE;
  float* H1    = F + OFF_H1ALL;
  float* srcE  = F + OFF_SRCE;
  float* tgtE  = F + OFF_TGTE;
  float* eproj = F + OFF_EPROJ;
  unsigned* wbf0 = (unsigned*)(F + OFF_WBF0);
  unsigned* wbf1 = (unsigned*)(F + OFF_WBF1);
  float* dTih0 = F + OFF_DTIH0;
  float* dThh0 = F + OFF_DTHH0;
  float* dTih1 = F + OFF_DTIH1;
  float* dThh1 = F + OFF_DTHH1;
  float* aT    = F + OFF_AT;
  float* e0h   = F + OFF_E0H0;
  float* e0c   = F + OFF_E0C;
  float* e1h   = F + OFF_E1H0;
  float* e1c   = F + OFF_E1C;
  float* dh0A  = F + OFF_DH0A;
  float* dh0B  = F + OFF_DH0B;
  float* dc0   = F + OFF_DC0;
  float* dh1A  = F + OFF_DH1A;
  float* dh1B  = F + OFF_DH1B;
  float* dc1   = F + OFF_DC1;
  float* ctx   = F + OFF_CTX;
  float* hA    = F + OFF_HA;
  float* hB    = F + OFF_HB;
  float* qg    = F + OFF_QG;
  float* scg   = F + OFF_SCG;
  unsigned* bar = (unsigned*)(F + OFF_BAR);
  float* hid   = (float*)d_ws;   // 2016 x 256 (2MB)

  // prep: weight packs/transposes, barrier zero, gather
  k_packbf<<<1024,256,0,stream>>>(eWhh0, wbf0, 2*1024*128);
  k_packbf<<<1024,256,0,stream>>>(eWhh1, wbf1, 2*1024*128);
  k_transpose<<<dim3(32,8),256,0,stream>>>(dWih0, dTih0, 2048,512,640,128);
  k_transpose<<<dim3(32,8),256,0,stream>>>(dWhh0, dThh0, 2048,512,512,0);
  k_transpose<<<dim3(32,8),256,0,stream>>>(dWih1, dTih1, 2048,512,512,0);
  k_transpose<<<dim3(32,8),256,0,stream>>>(dWhh1, dThh1, 2048,512,512,0);
  k_transpose<<<dim3(4,8),256,0,stream>>>(aW1,   aT,    256,512,1024,0);
  k_zero<<<3,256,0,stream>>>(F + OFF_BAR, 768);
  k_gather<<<((8192+2016)*32+255)/256,256,0,stream>>>(src, tgt, emb, srcE, tgtE);

  // encoder layer0: input proj + persistent scan
  k_mgemm<<<dim3(64,16),256,0,stream>>>(srcE, eWih0, eb0, Z, 8192,2048,128, 128,0,0);
  k_enc_scan<<<128,256,0,stream>>>(Z, wbf0, y0, hA, hB, e0h, e0c, bar);

  // encoder layer1
  k_mgemm<<<dim3(64,16),256,0,stream>>>(y0, eWih1, eb1, Z, 8192,2048,512, 512,0,0);
  k_enc_scan<<<128,256,0,stream>>>(Z, wbf1, y1, hA, hB, e1h, e1c, bar + 256);

  // enc_proj & decoder x-projection
  k_mgemm<<<dim3(64,2),256,0,stream>>>(y1, aW1, ab1, eproj, 8192,256,512, 1024,512,0);
  k_mgemm<<<dim3(16,16),256,0,stream>>>(tgtE, dWih0, db0, zpre, 2016,2048,128, 640,0,0);

  k_dec_init<<<64,256,0,stream>>>(e0h, e0c, e1h, e1c, dh0A, dc0, dh1A, dc1);

  // persistent decoder
  k_dec_scan<<<256,256,0,stream>>>(aT, eproj, aW2, ab2, y1, zpre, db1,
                                   dTih0, dThh0, dTih1, dThh1,
                                   dh0A, dh0B, dc0, dh1A, dh1B, dc1,
                                   qg, scg, ctx, H1, bar + 512);

  // output head
  k_mgemm<<<dim3(16,2),256,0,stream>>>(H1, oW1, ob1, hid, 2016,256,512, 512,0,1);
  k_mgemm<<<dim3(16,250),256,0,stream>>>(hid, oW2, ob2, F, 2016,32000,256, 256,0,2);
}

// Round 4
// 6673.215 us; speedup vs baseline: 4.4619x; 4.4619x over previous
//
#include <hip/hip_runtime.h>

// ---------------- problem constants ----------------
#define BB_ 32
#define SS_ 256
#define TD_ 63
#define EE_ 128
#define VV_ 32000

typedef unsigned short u16;
typedef __attribute__((ext_vector_type(8))) short short8v;
typedef __attribute__((ext_vector_type(4))) float f32x4;

__device__ __forceinline__ float sigf(float x){ return 1.0f/(1.0f+__expf(-x)); }
__device__ __forceinline__ float tanhf_fast(float x){ return 1.0f - 2.0f/(__expf(2.0f*x)+1.0f); }
__device__ __forceinline__ u16 f2bf(float f){
  unsigned u = __float_as_uint(f);
  u += 0x7fff + ((u >> 16) & 1);
  return (u16)(u >> 16);
}

// ---------------- d_out scratch layout (float offsets) ----------------
#define OFF_Z        0u
#define OFF_Y0       16777216u
#define OFF_Y1       20971520u
#define OFF_ZPRE     25165824u
#define OFF_H1ALL    29294592u
#define OFF_SRCE     30326784u
#define OFF_TGTE     31375360u
#define OFF_EPROJ    31633408u
#define OFF_ENCA0    33730560u
#define OFF_ENCA1    33992704u
#define OFF_DECA     34254848u
#define OFF_AT       38449152u
#define OFF_E0H      38580224u
#define OFF_E0C      38596608u
#define OFF_E1H      38612992u
#define OFF_E1C      38629376u
#define OFF_H0BUF    38645760u
#define OFF_H1BUF    38678528u
#define OFF_HEX      38711296u
#define OFF_QBUF     38744064u
#define OFF_CTXA     38752256u
#define OFF_BARS     38785536u

// ---------------- barriers (device-scope, fence-based) ----------------
__device__ __forceinline__ void icbar(unsigned* ctr, unsigned target){
  __syncthreads();
  if (threadIdx.x == 0){
    __builtin_amdgcn_fence(__ATOMIC_RELEASE, "agent");
    __hip_atomic_fetch_add(ctr, 1u, __ATOMIC_RELAXED, __HIP_MEMORY_SCOPE_AGENT);
    while (__hip_atomic_load(ctr, __ATOMIC_RELAXED, __HIP_MEMORY_SCOPE_AGENT) < target)
      __builtin_amdgcn_s_sleep(2);
    __builtin_amdgcn_fence(__ATOMIC_ACQUIRE, "agent");
  }
  __syncthreads();
}

// hierarchical: 16 groups x 16 blocks; group ctr at base[g*16], hi at base[256]
__device__ __forceinline__ void icbar2(unsigned* base, unsigned gen){
  __syncthreads();
  if (threadIdx.x == 0){
    unsigned g = blockIdx.x & 15u;
    __builtin_amdgcn_fence(__ATOMIC_RELEASE, "agent");
    unsigned old = __hip_atomic_fetch_add(&base[g*16], 1u, __ATOMIC_RELAXED, __HIP_MEMORY_SCOPE_AGENT);
    if ((old & 15u) == 15u)
      __hip_atomic_fetch_add(&base[256], 1u, __ATOMIC_RELAXED, __HIP_MEMORY_SCOPE_AGENT);
    while (__hip_atomic_load(&base[256], __ATOMIC_RELAXED, __HIP_MEMORY_SCOPE_AGENT) < gen*16u)
      __builtin_amdgcn_s_sleep(2);
    __builtin_amdgcn_fence(__ATOMIC_ACQUIRE, "agent");
  }
  __syncthreads();
}

// ---------------- utility kernels ----------------
__global__ void k_zero(float* __restrict__ p, int n){
  int i = blockIdx.x*256 + threadIdx.x;
  if (i < n) p[i] = 0.f;
}

__global__ void k_gather(const int* __restrict__ src, const int* __restrict__ tgt,
                         const float* __restrict__ emb,
                         float* __restrict__ src_e, float* __restrict__ tgt_e){
  int idx = blockIdx.x*256 + threadIdx.x;
  const int total = (8192 + 2016) * 32;
  if (idx >= total) return;
  int row = idx >> 5, j = idx & 31;
  int tok; float* dst;
  if (row < 8192){
    int s = row >> 5, b = row & 31;
    tok = src[b*SS_ + s];
    dst = src_e + (size_t)row*EE_;
  } else {
    int r2 = row - 8192;
    int t = r2 >> 5, b = r2 & 31;
    tok = tgt[b*64 + t];
    dst = tgt_e + (size_t)r2*EE_;
  }
  float4 v = *(const float4*)(emb + (size_t)tok*EE_ + j*4);
  *(float4*)(dst + j*4) = v;
}

// transpose (for aT): WT[(k/4)*C + c]*4 + (k%4)
__global__ __launch_bounds__(256) void k_transpose(
    const float* __restrict__ src, float* __restrict__ dst,
    int C, int Kd, int ldb, int off){
  __shared__ float tile[64][68];
  int c0 = blockIdx.x*64, k0 = blockIdx.y*64;
  int tid = threadIdx.x;
  for (int idx = tid; idx < 1024; idx += 256){
    int r = idx >> 4, j4 = idx & 15;
    float4 v = *(const float4*)(src + (size_t)(c0+r)*ldb + off + k0 + j4*4);
    tile[r][j4*4+0]=v.x; tile[r][j4*4+1]=v.y; tile[r][j4*4+2]=v.z; tile[r][j4*4+3]=v.w;
  }
  __syncthreads();
  for (int idx = tid; idx < 1024; idx += 256){
    int k4l = idx >> 6, cl = idx & 63;
    float4 v = make_float4(tile[cl][k4l*4+0], tile[cl][k4l*4+1],
                           tile[cl][k4l*4+2], tile[cl][k4l*4+3]);
    *(float4*)(dst + ((size_t)(k0/4 + k4l)*C + c0 + cl)*4) = v;
  }
}

// encoder A-fragment prep: out[((((d*8+us)*8+m)*8+kk)*64+l)*8+j]
__global__ void k_prep_encA(const float* __restrict__ W, u16* __restrict__ out){
  int idx = blockIdx.x*256 + threadIdx.x;
  if (idx >= 524288) return;
  int j = idx & 7, l = (idx>>3)&63, kk = (idx>>9)&7, m = (idx>>12)&7, us = (idx>>15)&7, d = (idx>>18)&1;
  int r = l & 15, g = r & 3, ut = r >> 2;
  int gcol = g*256 + us*32 + m*4 + ut;
  int k = kk*32 + (l>>4)*8 + j;
  out[idx] = f2bf(W[((size_t)d*1024 + gcol)*256 + k]);
}

// decoder A-fragment prep: out[(((B*2+cell)*32+kk)*64+l)*8+j]
__global__ void k_prep_decA(const float* __restrict__ Wih0, const float* __restrict__ Whh0,
                            const float* __restrict__ Wih1, const float* __restrict__ Whh1,
                            u16* __restrict__ out){
  int idx = blockIdx.x*256 + threadIdx.x;
  if (idx >= 8388608) return;
  int j = idx & 7, l = (idx>>3)&63, kk = (idx>>9)&31, cell = (idx>>14)&1, B = idx>>15;
  int r = l & 15;
  u16 v = 0;
  if (r < 8){
    int g = r & 3, u1 = r >> 2;
    int gcol = g*512 + B*2 + u1;
    int k = kk*32 + (l>>4)*8 + j;
    float wv;
    if (cell == 0) wv = (k < 512) ? Wih0[(size_t)gcol*640 + 128 + k] : Whh0[(size_t)gcol*512 + k - 512];
    else           wv = (k < 512) ? Wih1[(size_t)gcol*512 + k]       : Whh1[(size_t)gcol*512 + k - 512];
    v = f2bf(wv);
  }
  out[idx] = v;
}

// ---------------- bf16 MFMA GEMM (proven) ----------------
__global__ __launch_bounds__(256) void k_mgemm(
    const float* __restrict__ A, const float* __restrict__ Bm,
    const float* __restrict__ bias, float* __restrict__ C,
    int M, int N, int K, int ldb, int boff, int flags){
  __shared__ u16 As[128*72];
  __shared__ u16 Bs[128*72];
  int tid = threadIdx.x;
  int m0 = blockIdx.x*128, n0 = blockIdx.y*128;
  int l = tid & 63, w = tid >> 6;
  int wr = w >> 1, wc = w & 1;
  int lr = l & 15, lk = (l >> 4) * 8;
  f32x4 acc[4][4];
  #pragma unroll
  for (int m=0;m<4;m++)
    #pragma unroll
    for (int n=0;n<4;n++) acc[m][n] = (f32x4){0.f,0.f,0.f,0.f};

  int r = tid >> 1, half = tid & 1;
  bool aval = (m0 + r) < M;
  const float* arow = A + (size_t)(m0 + r)*K + half*32;
  const float* brow = Bm + (size_t)(n0 + r)*ldb + boff + half*32;
  u16* asd = &As[r*72 + half*32];
  u16* bsd = &Bs[r*72 + half*32];

  for (int k0 = 0; k0 < K; k0 += 64){
    #pragma unroll
    for (int j = 0; j < 4; j++){
      float4 x = make_float4(0.f,0.f,0.f,0.f), y = x;
      if (aval){
        x = *(const float4*)(arow + k0 + j*8);
        y = *(const float4*)(arow + k0 + j*8 + 4);
      }
      asd[j*8+0]=f2bf(x.x); asd[j*8+1]=f2bf(x.y); asd[j*8+2]=f2bf(x.z); asd[j*8+3]=f2bf(x.w);
      asd[j*8+4]=f2bf(y.x); asd[j*8+5]=f2bf(y.y); asd[j*8+6]=f2bf(y.z); asd[j*8+7]=f2bf(y.w);
      float4 p = *(const float4*)(brow + k0 + j*8);
      float4 q = *(const float4*)(brow + k0 + j*8 + 4);
      bsd[j*8+0]=f2bf(p.x); bsd[j*8+1]=f2bf(p.y); bsd[j*8+2]=f2bf(p.z); bsd[j*8+3]=f2bf(p.w);
      bsd[j*8+4]=f2bf(q.x); bsd[j*8+5]=f2bf(q.y); bsd[j*8+6]=f2bf(q.z); bsd[j*8+7]=f2bf(q.w);
    }
    __syncthreads();
    #pragma unroll
    for (int kk = 0; kk < 2; kk++){
      short8v aF[4], bF[4];
      #pragma unroll
      for (int m = 0; m < 4; m++)
        aF[m] = *(short8v*)&As[(wr*64 + m*16 + lr)*72 + kk*32 + lk];
      #pragma unroll
      for (int n = 0; n < 4; n++)
        bF[n] = *(short8v*)&Bs[(wc*64 + n*16 + lr)*72 + kk*32 + lk];
      #pragma unroll
      for (int m = 0; m < 4; m++)
        #pragma unroll
        for (int n = 0; n < 4; n++)
          acc[m][n] = __builtin_amdgcn_mfma_f32_16x16x32_bf16(aF[m], bF[n], acc[m][n], 0, 0, 0);
    }
    __syncthreads();
  }

  #pragma unroll
  for (int m = 0; m < 4; m++){
    int gr0 = m0 + wr*64 + m*16 + (l >> 4)*4;
    #pragma unroll
    for (int n = 0; n < 4; n++){
      int gc = n0 + wc*64 + n*16 + (l & 15);
      float bv = bias[gc];
      #pragma unroll
      for (int j = 0; j < 4; j++){
        int gr = gr0 + j;
        if (gr >= M) continue;
        float v = acc[m][n][j] + bv;
        if (flags & 1) v = fmaxf(v, 0.f);
        if (flags & 2){
          int t = gr >> 5, b = gr & 31;
          C[((size_t)(b*63 + t))*(size_t)N + gc] = v;
        } else {
          C[(size_t)gr*N + gc] = v;
        }
      }
    }
  }
}

// ---------------- persistent MFMA encoder scan ----------------
// 32 blocks: us(8) x bh(2) x d(2). Domain (d,bh): 8 blocks, units split.
// A-frags in LDS (64KB), h staged bf16 (pitch 592B), c in regs.
__global__ __launch_bounds__(256) void k_enc_scan(
    const float* __restrict__ Z, const u16* __restrict__ encA,
    float* __restrict__ y, float* __restrict__ hexb,
    float* __restrict__ hfin, float* __restrict__ cfin,
    unsigned* __restrict__ bars){
  extern __shared__ char smem[];
  char* ldsA = smem;            // 65536
  char* bstE = smem + 65536;    // 16*592 = 9472
  int blk = blockIdx.x, tid = threadIdx.x;
  int us = blk & 7, bh = (blk>>3)&1, d = blk>>4;
  int dom = d*2 + bh;
  unsigned* ctr = bars + dom*16;
  int w = tid >> 6, l = tid & 63;
  int lr = l & 15, lk = l >> 4;
  { const uint4* s = (const uint4*)(encA + (size_t)(d*8+us)*32768);
    uint4* dst = (uint4*)ldsA;
    for (int i = tid; i < 4096; i += 256) dst[i] = s[i]; }
  { uint4* b4 = (uint4*)bstE;
    uint4 zz = make_uint4(0,0,0,0);
    for (int i = tid; i < 592; i += 256) b4[i] = zz; }
  float c0 = 0.f, c1 = 0.f;
  int b_g = bh*16 + lr;
  int u0 = (w*2+0)*4 + lk, u1_ = (w*2+1)*4 + lk;
  int uc0 = us*32 + u0, uc1 = us*32 + u1_;
  __syncthreads();
  for (int i = 0; i < 256; i++){
    int t = d ? (255 - i) : i;
    const float* zr = Z + ((size_t)t*32 + b_g)*2048 + d*1024;
    float za[4], zb[4];
    #pragma unroll
    for (int j = 0; j < 4; j++){ za[j] = zr[j*256 + uc0]; zb[j] = zr[j*256 + uc1]; }
    f32x4 acc0 = (f32x4){0.f,0.f,0.f,0.f};
    f32x4 acc1 = (f32x4){0.f,0.f,0.f,0.f};
    #pragma unroll
    for (int kk = 0; kk < 8; kk++){
      short8v bF = *(const short8v*)(bstE + lr*592 + kk*64 + lk*16);
      short8v a0 = *(const short8v*)(ldsA + (((w*2+0)*8 + kk)*64 + l)*16);
      short8v a1 = *(const short8v*)(ldsA + (((w*2+1)*8 + kk)*64 + l)*16);
      acc0 = __builtin_amdgcn_mfma_f32_16x16x32_bf16(a0, bF, acc0, 0, 0, 0);
      acc1 = __builtin_amdgcn_mfma_f32_16x16x32_bf16(a1, bF, acc1, 0, 0, 0);
    }
    float z0 = acc0[0]+za[0], z1 = acc0[1]+za[1], z2 = acc0[2]+za[2], z3 = acc0[3]+za[3];
    float cn = sigf(z1)*c0 + sigf(z0)*tanhf_fast(z2);
    float hn0 = sigf(z3)*tanhf_fast(cn); c0 = cn;
    z0 = acc1[0]+zb[0]; z1 = acc1[1]+zb[1]; z2 = acc1[2]+zb[2]; z3 = acc1[3]+zb[3];
    cn = sigf(z1)*c1 + sigf(z0)*tanhf_fast(z2);
    float hn1 = sigf(z3)*tanhf_fast(cn); c1 = cn;
    size_t yr = ((size_t)t*32 + b_g)*512 + d*256;
    y[yr + uc0] = hn0; y[yr + uc1] = hn1;
    float* hx = hexb + ((size_t)(dom*2 + (i&1)))*4096;
    hx[lr*256 + uc0] = hn0; hx[lr*256 + uc1] = hn1;
    if (i == 255){
      size_t fb = ((size_t)d*32 + b_g)*256;
      hfin[fb + uc0] = hn0; hfin[fb + uc1] = hn1;
      cfin[fb + uc0] = c0;  cfin[fb + uc1] = c1;
      break;
    }
    icbar(ctr, (unsigned)(i+1)*8u);
    {
      int bs = tid >> 4, seg = tid & 15;
      const float2* src = (const float2*)(hexb + ((size_t)(dom*2 + (i&1)))*4096 + bs*256 + seg*16);
      unsigned pk[8];
      #pragma unroll
      for (int s2 = 0; s2 < 8; s2++){
        float2 v = src[s2];
        pk[s2] = (unsigned)f2bf(v.x) | ((unsigned)f2bf(v.y) << 16);
      }
      uint4* dsd = (uint4*)(bstE + bs*592 + seg*32);
      dsd[0] = make_uint4(pk[0],pk[1],pk[2],pk[3]);
      dsd[1] = make_uint4(pk[4],pk[5],pk[6],pk[7]);
    }
    __syncthreads();
  }
}

// ---------------- persistent MFMA decoder scan ----------------
// 256 blocks, single hierarchical domain. 4 phases/step.
__global__ __launch_bounds__(256) void k_dec_scan(
    const float* __restrict__ aT, const float* __restrict__ eproj,
    const float* __restrict__ aW2, const float* __restrict__ y1,
    const float* __restrict__ zpre, const float* __restrict__ db1,
    const u16* __restrict__ decA,
    const float* __restrict__ e0c, const float* __restrict__ e1c,
    float* __restrict__ h0buf, float* __restrict__ h1buf,
    float* __restrict__ qbuf, float* __restrict__ ctxa,
    float* __restrict__ H1all, unsigned* __restrict__ bars){
  extern __shared__ char smem[];
  char* ldsA = smem;                 // 65536 (2 cells x 32KB)
  char* bst  = smem + 65536;         // 32*2128 = 68096
  float* scr = (float*)(smem + 133632); // 4608B
  int Bid = blockIdx.x, tid = threadIdx.x;
  int w = tid >> 6, l = tid & 63;
  int n_ = w & 1, kh = w >> 1;
  int lr = l & 15, lk = l >> 4;
  { const uint4* s = (const uint4*)(decA + (size_t)Bid*32768);
    uint4* d4 = (uint4*)ldsA;
    for (int i = tid; i < 4096; i += 256) d4[i] = s[i]; }
  int b_att = Bid >> 3, sub = Bid & 7;
  bool epi = (kh == 1) && (lk < 2);
  int u1 = lk & 1;
  int b_ep = n_*16 + lr;
  int ug = Bid*2 + u1;
  float c0r = 0.f, c1r = 0.f, d0 = 0.f, d1 = 0.f, d2 = 0.f, d3 = 0.f;
  if (epi){
    int dd = ug >> 8, uu = ug & 255;
    c0r = e0c[((size_t)dd*32 + b_ep)*256 + uu];
    c1r = e1c[((size_t)dd*32 + b_ep)*256 + uu];
    d0 = db1[0*512 + ug]; d1 = db1[1*512 + ug];
    d2 = db1[2*512 + ug]; d3 = db1[3*512 + ug];
  }
  __syncthreads();
  unsigned gen = 0;
  for (int t = 0; t < TD_; t++){
    int hp = t & 1, cp = t & 1;
    // ===== phase 1: q slice =====
    {
      float* h1s = scr; float* qred = scr + 512;
      h1s[tid]       = h1buf[(size_t)hp*16384 + b_att*512 + tid];
      h1s[tid + 256] = h1buf[(size_t)hp*16384 + b_att*512 + 256 + tid];
      if (tid < 64) ctxa[(size_t)(1-cp)*16640 + b_att*520 + sub*64 + tid] = 0.f;
      if (sub == 0 && tid >= 64 && tid < 72)
        ctxa[(size_t)(1-cp)*16640 + b_att*520 + 448 + tid] = 0.f;
      __syncthreads();
      int c32 = tid & 31, kc = tid >> 5;
      const float4* w4 = (const float4*)aT;
      const float4* h4 = (const float4*)h1s;
      float a = 0.f;
      #pragma unroll 4
      for (int jj = 0; jj < 16; jj++){
        int k4 = kc*16 + jj;
        float4 wv = w4[(size_t)k4*256 + sub*32 + c32];
        float4 hv = h4[k4];
        a += wv.x*hv.x + wv.y*hv.y + wv.z*hv.z + wv.w*hv.w;
      }
      qred[c32*9 + kc] = a;
      __syncthreads();
      if (tid < 32){
        float q = 0.f;
        #pragma unroll
        for (int k = 0; k < 8; k++) q += qred[tid*9 + k];
        qbuf[b_att*256 + sub*32 + tid] = q;
      }
    }
    icbar2(bars, ++gen);
    // ===== phase 2: scores + exp + partial ctx =====
    {
      float* qs = scr; float* w2s = scr + 256; float* sred = scr + 512; float* esc = scr + 800;
      qs[tid] = qbuf[b_att*256 + tid];
      w2s[tid] = aW2[tid];
      __syncthreads();
      int sl = tid >> 3, hc = tid & 7;
      int s = sub*32 + sl;
      const float4* ep = (const float4*)(eproj + ((size_t)s*32 + b_att)*256 + hc*32);
      const float4* q4 = (const float4*)(qs + hc*32);
      const float4* w24 = (const float4*)(w2s + hc*32);
      float acc = 0.f;
      #pragma unroll
      for (int k = 0; k < 8; k++){
        float4 e = ep[k], qq = q4[k], ww = w24[k];
        acc += tanhf_fast(e.x+qq.x)*ww.x + tanhf_fast(e.y+qq.y)*ww.y
             + tanhf_fast(e.z+qq.z)*ww.z + tanhf_fast(e.w+qq.w)*ww.w;
      }
      sred[sl*9 + hc] = acc;
      __syncthreads();
      if (hc == 0){
        float r = 0.f;
        #pragma unroll
        for (int k = 0; k < 8; k++) r += sred[sl*9 + k];
        esc[sl] = __expf(r);   // skip max & b2: softmax shift-invariant, |score|<=~10
      }
      __syncthreads();
      float a0 = 0.f, a1 = 0.f;
      #pragma unroll 4
      for (int s2 = 0; s2 < 32; s2++){
        float e = esc[s2];
        float2 v = *(const float2*)(y1 + ((size_t)(sub*32 + s2)*32 + b_att)*512 + tid*2);
        a0 += e*v.x; a1 += e*v.y;
      }
      atomicAdd(&ctxa[(size_t)cp*16640 + b_att*520 + tid*2], a0);
      atomicAdd(&ctxa[(size_t)cp*16640 + b_att*520 + tid*2 + 1], a1);
      if (tid == 0){
        float ss = 0.f;
        for (int k = 0; k < 32; k++) ss += esc[k];
        atomicAdd(&ctxa[(size_t)cp*16640 + b_att*520 + 512], ss);
      }
    }
    icbar2(bars, ++gen);
    // ===== phase 3: cell0 =====
    {
      int b_s = tid >> 3, pr = tid & 7;
      const float* A_ = ctxa + (size_t)cp*16640 + b_s*520;
      const float* B_ = h0buf + (size_t)hp*16384 + b_s*512;
      float sc_ = 1.0f / A_[512];
      for (int i8 = 0; i8 < 16; i8++){
        unsigned pk[4];
        #pragma unroll
        for (int pj = 0; pj < 4; pj++){
          int p = pr*64 + i8*4 + pj;
          float2 v;
          if (p < 256){ v = *(const float2*)(A_ + 2*p); v.x *= sc_; v.y *= sc_; }
          else        { v = *(const float2*)(B_ + 2*p - 512); }
          pk[pj] = (unsigned)f2bf(v.x) | ((unsigned)f2bf(v.y) << 16);
        }
        *(uint4*)(bst + b_s*2128 + pr*256 + i8*16) = make_uint4(pk[0],pk[1],pk[2],pk[3]);
      }
      __syncthreads();
      f32x4 acc = (f32x4){0.f,0.f,0.f,0.f};
      #pragma unroll
      for (int kk = kh*16; kk < kh*16 + 16; kk++){
        short8v aF = *(const short8v*)(ldsA + (kk*64 + l)*16);
        short8v bF = *(const short8v*)(bst + (n_*16 + lr)*2128 + kk*64 + lk*16);
        acc = __builtin_amdgcn_mfma_f32_16x16x32_bf16(aF, bF, acc, 0, 0, 0);
      }
      float* zred = scr;
      if (kh == 0) *(f32x4*)&zred[(n_*64 + l)*4] = acc;
      __syncthreads();
      if (epi){
        f32x4 o = *(f32x4*)&zred[(n_*64 + l)*4];
        const float* zp = zpre + ((size_t)t*32 + b_ep)*2048 + ug;
        float z0 = acc[0]+o[0]+zp[0],    z1 = acc[1]+o[1]+zp[512];
        float z2 = acc[2]+o[2]+zp[1024], z3 = acc[3]+o[3]+zp[1536];
        float cn = sigf(z1)*c0r + sigf(z0)*tanhf_fast(z2);
        float hn = sigf(z3)*tanhf_fast(cn);
        c0r = cn;
        h0buf[(size_t)(1-hp)*16384 + b_ep*512 + ug] = hn;
      }
    }
    icbar2(bars, ++gen);
    // ===== phase 4: cell1 =====
    {
      int b_s = tid >> 3, pr = tid & 7;
      const float* A_ = h0buf + (size_t)(1-hp)*16384 + b_s*512;
      const float* B_ = h1buf + (size_t)hp*16384 + b_s*512;
      for (int i8 = 0; i8 < 16; i8++){
        unsigned pk[4];
        #pragma unroll
        for (int pj = 0; pj < 4; pj++){
          int p = pr*64 + i8*4 + pj;
          float2 v = (p < 256) ? *(const float2*)(A_ + 2*p)
                               : *(const float2*)(B_ + 2*p - 512);
          pk[pj] = (unsigned)f2bf(v.x) | ((unsigned)f2bf(v.y) << 16);
        }
        *(uint4*)(bst + b_s*2128 + pr*256 + i8*16) = make_uint4(pk[0],pk[1],pk[2],pk[3]);
      }
      __syncthreads();
      f32x4 acc = (f32x4){0.f,0.f,0.f,0.f};
      #pragma unroll
      for (int kk = kh*16; kk < kh*16 + 16; kk++){
        short8v aF = *(const short8v*)(ldsA + 32768 + (kk*64 + l)*16);
        short8v bF = *(const short8v*)(bst + (n_*16 + lr)*2128 + kk*64 + lk*16);
        acc = __builtin_amdgcn_mfma_f32_16x16x32_bf16(aF, bF, acc, 0, 0, 0);
      }
      float* zred = scr;
      if (kh == 0) *(f32x4*)&zred[(n_*64 + l)*4] = acc;
      __syncthreads();
      if (epi){
        f32x4 o = *(f32x4*)&zred[(n_*64 + l)*4];
        float z0 = acc[0]+o[0]+d0, z1 = acc[1]+o[1]+d1;
        float z2 = acc[2]+o[2]+d2, z3 = acc[3]+o[3]+d3;
        float cn = sigf(z1)*c1r + sigf(z0)*tanhf_fast(z2);
        float hn = sigf(z3)*tanhf_fast(cn);
        c1r = cn;
        h1buf[(size_t)(1-hp)*16384 + b_ep*512 + ug] = hn;
        H1all[((size_t)t*32 + b_ep)*512 + ug] = hn;
      }
    }
    if (t < TD_-1) icbar2(bars, ++gen);
  }
}

// decoder h-state init (parity 0)
__global__ void k_dinit(const float* __restrict__ eh0, const float* __restrict__ eh1,
                        float* __restrict__ h0b, float* __restrict__ h1b){
  int idx = blockIdx.x*256 + threadIdx.x;
  if (idx >= 16384) return;
  int b = idx >> 9, u = idx & 511, dd = u >> 8, uu = u & 255;
  h0b[idx] = eh0[(dd*32 + b)*256 + uu];
  h1b[idx] = eh1[(dd*32 + b)*256 + uu];
}

// ---------------- host launch ----------------
extern "C" void kernel_launch(void* const* d_in, const int* in_sizes, int n_in,
                              void* d_out, int out_size, void* d_ws, size_t ws_size,
                              hipStream_t stream){
  (void)in_sizes; (void)n_in; (void)out_size; (void)ws_size;
  const int*   src   = (const int*)d_in[0];
  const int*   tgt   = (const int*)d_in[1];
  const float* emb   = (const float*)d_in[2];
  const float* eWih0 = (const float*)d_in[3];
  const float* eWhh0 = (const float*)d_in[4];
  const float* eb0   = (const float*)d_in[5];
  const float* eWih1 = (const float*)d_in[6];
  const float* eWhh1 = (const float*)d_in[7];
  const float* eb1   = (const float*)d_in[8];
  const float* dWih0 = (const float*)d_in[9];
  const float* dWhh0 = (const float*)d_in[10];
  const float* db0   = (const float*)d_in[11];
  const float* dWih1 = (const float*)d_in[12];
  const float* dWhh1 = (const float*)d_in[13];
  const float* db1   = (const float*)d_in[14];
  const float* aW1   = (const float*)d_in[15];
  const float* ab1   = (const float*)d_in[16];
  const float* aW2   = (const float*)d_in[17];
  const float* oW1   = (const float*)d_in[19];
  const float* ob1   = (const float*)d_in[20];
  const float* oW2   = (const float*)d_in[21];
  const float* ob2   = (const float*)d_in[22];

  float* F = (float*)d_out;
  float* Z     = F + OFF_Z;
  float* y0    = F + OFF_Y0;
  float* y1    = F + OFF_Y1;
  float* zpre  = F + OFF_ZPRE;
  float* H1    = F + OFF_H1ALL;
  float* srcE  = F + OFF_SRCE;
  float* tgtE  = F + OFF_TGTE;
  float* eproj = F + OFF_EPROJ;
  u16*   encA0 = (u16*)(F + OFF_ENCA0);
  u16*   encA1 = (u16*)(F + OFF_ENCA1);
  u16*   decA  = (u16*)(F + OFF_DECA);
  float* aT    = F + OFF_AT;
  float* e0h   = F + OFF_E0H;
  float* e0c   = F + OFF_E0C;
  float* e1h   = F + OFF_E1H;
  float* e1c   = F + OFF_E1C;
  float* h0buf = F + OFF_H0BUF;
  float* h1buf = F + OFF_H1BUF;
  float* hexb  = F + OFF_HEX;
  float* qbuf  = F + OFF_QBUF;
  float* ctxa  = F + OFF_CTXA;
  unsigned* bars = (unsigned*)(F + OFF_BARS);
  float* hid   = (float*)d_ws;

  hipFuncSetAttribute((const void*)k_enc_scan, hipFuncAttributeMaxDynamicSharedMemorySize, 75008);
  hipFuncSetAttribute((const void*)k_dec_scan, hipFuncAttributeMaxDynamicSharedMemorySize, 138240);

  // zero ctx accumulators + barrier counters (contiguous)
  k_zero<<<(34304+255)/256,256,0,stream>>>(F + OFF_CTXA, 34304);
  k_gather<<<((8192+2016)*32+255)/256,256,0,stream>>>(src, tgt, emb, srcE, tgtE);
  k_prep_encA<<<2048,256,0,stream>>>(eWhh0, encA0);
  k_prep_encA<<<2048,256,0,stream>>>(eWhh1, encA1);
  k_prep_decA<<<32768,256,0,stream>>>(dWih0, dWhh0, dWih1, dWhh1, decA);
  k_transpose<<<dim3(4,8),256,0,stream>>>(aW1, aT, 256,512,1024,0);

  // encoder layer0
  k_mgemm<<<dim3(64,16),256,0,stream>>>(srcE, eWih0, eb0, Z, 8192,2048,128, 128,0,0);
  k_enc_scan<<<32,256,75008,stream>>>(Z, encA0, y0, hexb, e0h, e0c, bars);
  // encoder layer1
  k_mgemm<<<dim3(64,16),256,0,stream>>>(y0, eWih1, eb1, Z, 8192,2048,512, 512,0,0);
  k_enc_scan<<<32,256,75008,stream>>>(Z, encA1, y1, hexb, e1h, e1c, bars + 320);

  // projections
  k_mgemm<<<dim3(64,2),256,0,stream>>>(y1, aW1, ab1, eproj, 8192,256,512, 1024,512,0);
  k_mgemm<<<dim3(16,16),256,0,stream>>>(tgtE, dWih0, db0, zpre, 2016,2048,128, 640,0,0);
  k_dinit<<<64,256,0,stream>>>(e0h, e1h, h0buf, h1buf);

  // decoder
  k_dec_scan<<<256,256,138240,stream>>>(aT, eproj, aW2, y1, zpre, db1, decA,
                                        e0c, e1c, h0buf, h1buf, qbuf, ctxa, H1, bars + 640);

  // output head
  k_mgemm<<<dim3(16,2),256,0,stream>>>(H1, oW1, ob1, hid, 2016,256,512, 512,0,1);
  k_mgemm<<<dim3(16,250),256,0,stream>>>(hid, oW2, ob2, F, 2016,32000,256, 256,0,2);
}

// Round 5
// 4903.211 us; speedup vs baseline: 6.0726x; 1.3610x over previous
//
#include <hip/hip_runtime.h>

// ---------------- problem constants ----------------
#define BB_ 32
#define SS_ 256
#define TD_ 63
#define EE_ 128
#define VV_ 32000

typedef unsigned short u16;
typedef __attribute__((ext_vector_type(8))) short short8v;
typedef __attribute__((ext_vector_type(4))) float f32x4;

__device__ __forceinline__ float sigf(float x){ return 1.0f/(1.0f+__expf(-x)); }
__device__ __forceinline__ float tanhf_fast(float x){ return 1.0f - 2.0f/(__expf(2.0f*x)+1.0f); }
__device__ __forceinline__ u16 f2bf(float f){
  unsigned u = __float_as_uint(f);
  u += 0x7fff + ((u >> 16) & 1);
  return (u16)(u >> 16);
}

// ---- coherent (agent-scope, L3-coherence-point) payload accessors ----
__device__ __forceinline__ float ald(const float* p){
  return __hip_atomic_load(p, __ATOMIC_RELAXED, __HIP_MEMORY_SCOPE_AGENT);
}
__device__ __forceinline__ void ast(float* p, float v){
  __hip_atomic_store(p, v, __ATOMIC_RELAXED, __HIP_MEMORY_SCOPE_AGENT);
}
__device__ __forceinline__ float2 ald2(const float* p){
  unsigned long long u = __hip_atomic_load((const unsigned long long*)p,
                          __ATOMIC_RELAXED, __HIP_MEMORY_SCOPE_AGENT);
  float2 r;
  r.x = __uint_as_float((unsigned)u);
  r.y = __uint_as_float((unsigned)(u >> 32));
  return r;
}
__device__ __forceinline__ void vdrain(){ asm volatile("s_waitcnt vmcnt(0)" ::: "memory"); }

// ---------------- d_out scratch layout (float offsets) ----------------
#define OFF_Z        0u
#define OFF_Y0       16777216u
#define OFF_Y1       20971520u
#define OFF_ZPRE     25165824u
#define OFF_H1ALL    29294592u
#define OFF_SRCE     30326784u
#define OFF_TGTE     31375360u
#define OFF_EPROJ    31633408u
#define OFF_ENCA0    33730560u
#define OFF_ENCA1    33992704u
#define OFF_DECA     34254848u
#define OFF_AT       38449152u
#define OFF_E0H      38580224u
#define OFF_E0C      38596608u
#define OFF_E1H      38612992u
#define OFF_E1C      38629376u
#define OFF_H0BUF    38645760u
#define OFF_H1BUF    38678528u
#define OFF_HEX      38711296u
#define OFF_QBUF     38744064u
#define OFF_CTXA     38752256u
#define OFF_BARS     38785536u

// ---------------- fence-free barriers (payload via coherent atomics) ----------------
// producer ordering: every wave drains vmcnt(0) (atomic stores acked at coherence
// point) BEFORE the arrive-add; consumers' payload loads are coherent atomic loads
// issued after the poll succeeds. No L2 invalidation -> read-only data stays cached.
__device__ __forceinline__ void icbar(unsigned* ctr, unsigned target){
  vdrain();
  __syncthreads();
  if (threadIdx.x == 0){
    __hip_atomic_fetch_add(ctr, 1u, __ATOMIC_RELAXED, __HIP_MEMORY_SCOPE_AGENT);
    while (__hip_atomic_load(ctr, __ATOMIC_RELAXED, __HIP_MEMORY_SCOPE_AGENT) < target)
      __builtin_amdgcn_s_sleep(2);
  }
  __syncthreads();
  asm volatile("" ::: "memory");
}

// hierarchical: 16 groups x 16 blocks; group ctr at base[g*16], hi at base[256]
__device__ __forceinline__ void icbar2(unsigned* base, unsigned gen){
  vdrain();
  __syncthreads();
  if (threadIdx.x == 0){
    unsigned g = blockIdx.x & 15u;
    unsigned old = __hip_atomic_fetch_add(&base[g*16], 1u, __ATOMIC_RELAXED, __HIP_MEMORY_SCOPE_AGENT);
    if ((old & 15u) == 15u)
      __hip_atomic_fetch_add(&base[256], 1u, __ATOMIC_RELAXED, __HIP_MEMORY_SCOPE_AGENT);
    while (__hip_atomic_load(&base[256], __ATOMIC_RELAXED, __HIP_MEMORY_SCOPE_AGENT) < gen*16u)
      __builtin_amdgcn_s_sleep(2);
  }
  __syncthreads();
  asm volatile("" ::: "memory");
}

// ---------------- utility kernels ----------------
__global__ void k_zero(float* __restrict__ p, int n){
  int i = blockIdx.x*256 + threadIdx.x;
  if (i < n) p[i] = 0.f;
}

__global__ void k_gather(const int* __restrict__ src, const int* __restrict__ tgt,
                         const float* __restrict__ emb,
                         float* __restrict__ src_e, float* __restrict__ tgt_e){
  int idx = blockIdx.x*256 + threadIdx.x;
  const int total = (8192 + 2016) * 32;
  if (idx >= total) return;
  int row = idx >> 5, j = idx & 31;
  int tok; float* dst;
  if (row < 8192){
    int s = row >> 5, b = row & 31;
    tok = src[b*SS_ + s];
    dst = src_e + (size_t)row*EE_;
  } else {
    int r2 = row - 8192;
    int t = r2 >> 5, b = r2 & 31;
    tok = tgt[b*64 + t];
    dst = tgt_e + (size_t)r2*EE_;
  }
  float4 v = *(const float4*)(emb + (size_t)tok*EE_ + j*4);
  *(float4*)(dst + j*4) = v;
}

// transpose (for aT): WT[(k/4)*C + c]*4 + (k%4)
__global__ __launch_bounds__(256) void k_transpose(
    const float* __restrict__ src, float* __restrict__ dst,
    int C, int Kd, int ldb, int off){
  __shared__ float tile[64][68];
  int c0 = blockIdx.x*64, k0 = blockIdx.y*64;
  int tid = threadIdx.x;
  for (int idx = tid; idx < 1024; idx += 256){
    int r = idx >> 4, j4 = idx & 15;
    float4 v = *(const float4*)(src + (size_t)(c0+r)*ldb + off + k0 + j4*4);
    tile[r][j4*4+0]=v.x; tile[r][j4*4+1]=v.y; tile[r][j4*4+2]=v.z; tile[r][j4*4+3]=v.w;
  }
  __syncthreads();
  for (int idx = tid; idx < 1024; idx += 256){
    int k4l = idx >> 6, cl = idx & 63;
    float4 v = make_float4(tile[cl][k4l*4+0], tile[cl][k4l*4+1],
                           tile[cl][k4l*4+2], tile[cl][k4l*4+3]);
    *(float4*)(dst + ((size_t)(k0/4 + k4l)*C + c0 + cl)*4) = v;
  }
}

// encoder A-fragment prep: out[((((d*8+us)*8+m)*8+kk)*64+l)*8+j]
__global__ void k_prep_encA(const float* __restrict__ W, u16* __restrict__ out){
  int idx = blockIdx.x*256 + threadIdx.x;
  if (idx >= 524288) return;
  int j = idx & 7, l = (idx>>3)&63, kk = (idx>>9)&7, m = (idx>>12)&7, us = (idx>>15)&7, d = (idx>>18)&1;
  int r = l & 15, g = r & 3, ut = r >> 2;
  int gcol = g*256 + us*32 + m*4 + ut;
  int k = kk*32 + (l>>4)*8 + j;
  out[idx] = f2bf(W[((size_t)d*1024 + gcol)*256 + k]);
}

// decoder A-fragment prep: out[(((B*2+cell)*32+kk)*64+l)*8+j]
__global__ void k_prep_decA(const float* __restrict__ Wih0, const float* __restrict__ Whh0,
                            const float* __restrict__ Wih1, const float* __restrict__ Whh1,
                            u16* __restrict__ out){
  int idx = blockIdx.x*256 + threadIdx.x;
  if (idx >= 8388608) return;
  int j = idx & 7, l = (idx>>3)&63, kk = (idx>>9)&31, cell = (idx>>14)&1, B = idx>>15;
  int r = l & 15;
  u16 v = 0;
  if (r < 8){
    int g = r & 3, u1 = r >> 2;
    int gcol = g*512 + B*2 + u1;
    int k = kk*32 + (l>>4)*8 + j;
    float wv;
    if (cell == 0) wv = (k < 512) ? Wih0[(size_t)gcol*640 + 128 + k] : Whh0[(size_t)gcol*512 + k - 512];
    else           wv = (k < 512) ? Wih1[(size_t)gcol*512 + k]       : Whh1[(size_t)gcol*512 + k - 512];
    v = f2bf(wv);
  }
  out[idx] = v;
}

// ---------------- bf16 MFMA GEMM (proven) ----------------
__global__ __launch_bounds__(256) void k_mgemm(
    const float* __restrict__ A, const float* __restrict__ Bm,
    const float* __restrict__ bias, float* __restrict__ C,
    int M, int N, int K, int ldb, int boff, int flags){
  __shared__ u16 As[128*72];
  __shared__ u16 Bs[128*72];
  int tid = threadIdx.x;
  int m0 = blockIdx.x*128, n0 = blockIdx.y*128;
  int l = tid & 63, w = tid >> 6;
  int wr = w >> 1, wc = w & 1;
  int lr = l & 15, lk = (l >> 4) * 8;
  f32x4 acc[4][4];
  #pragma unroll
  for (int m=0;m<4;m++)
    #pragma unroll
    for (int n=0;n<4;n++) acc[m][n] = (f32x4){0.f,0.f,0.f,0.f};

  int r = tid >> 1, half = tid & 1;
  bool aval = (m0 + r) < M;
  const float* arow = A + (size_t)(m0 + r)*K + half*32;
  const float* brow = Bm + (size_t)(n0 + r)*ldb + boff + half*32;
  u16* asd = &As[r*72 + half*32];
  u16* bsd = &Bs[r*72 + half*32];

  for (int k0 = 0; k0 < K; k0 += 64){
    #pragma unroll
    for (int j = 0; j < 4; j++){
      float4 x = make_float4(0.f,0.f,0.f,0.f), y = x;
      if (aval){
        x = *(const float4*)(arow + k0 + j*8);
        y = *(const float4*)(arow + k0 + j*8 + 4);
      }
      asd[j*8+0]=f2bf(x.x); asd[j*8+1]=f2bf(x.y); asd[j*8+2]=f2bf(x.z); asd[j*8+3]=f2bf(x.w);
      asd[j*8+4]=f2bf(y.x); asd[j*8+5]=f2bf(y.y); asd[j*8+6]=f2bf(y.z); asd[j*8+7]=f2bf(y.w);
      float4 p = *(const float4*)(brow + k0 + j*8);
      float4 q = *(const float4*)(brow + k0 + j*8 + 4);
      bsd[j*8+0]=f2bf(p.x); bsd[j*8+1]=f2bf(p.y); bsd[j*8+2]=f2bf(p.z); bsd[j*8+3]=f2bf(p.w);
      bsd[j*8+4]=f2bf(q.x); bsd[j*8+5]=f2bf(q.y); bsd[j*8+6]=f2bf(q.z); bsd[j*8+7]=f2bf(q.w);
    }
    __syncthreads();
    #pragma unroll
    for (int kk = 0; kk < 2; kk++){
      short8v aF[4], bF[4];
      #pragma unroll
      for (int m = 0; m < 4; m++)
        aF[m] = *(short8v*)&As[(wr*64 + m*16 + lr)*72 + kk*32 + lk];
      #pragma unroll
      for (int n = 0; n < 4; n++)
        bF[n] = *(short8v*)&Bs[(wc*64 + n*16 + lr)*72 + kk*32 + lk];
      #pragma unroll
      for (int m = 0; m < 4; m++)
        #pragma unroll
        for (int n = 0; n < 4; n++)
          acc[m][n] = __builtin_amdgcn_mfma_f32_16x16x32_bf16(aF[m], bF[n], acc[m][n], 0, 0, 0);
    }
    __syncthreads();
  }

  #pragma unroll
  for (int m = 0; m < 4; m++){
    int gr0 = m0 + wr*64 + m*16 + (l >> 4)*4;
    #pragma unroll
    for (int n = 0; n < 4; n++){
      int gc = n0 + wc*64 + n*16 + (l & 15);
      float bv = bias[gc];
      #pragma unroll
      for (int j = 0; j < 4; j++){
        int gr = gr0 + j;
        if (gr >= M) continue;
        float v = acc[m][n][j] + bv;
        if (flags & 1) v = fmaxf(v, 0.f);
        if (flags & 2){
          int t = gr >> 5, b = gr & 31;
          C[((size_t)(b*63 + t))*(size_t)N + gc] = v;
        } else {
          C[(size_t)gr*N + gc] = v;
        }
      }
    }
  }
}

// ---------------- persistent MFMA encoder scan ----------------
// 32 blocks: us(8) x bh(2) x d(2). Domain (d,bh): 8 blocks, units split.
__global__ __launch_bounds__(256) void k_enc_scan(
    const float* __restrict__ Z, const u16* __restrict__ encA,
    float* __restrict__ y, float* __restrict__ hexb,
    float* __restrict__ hfin, float* __restrict__ cfin,
    unsigned* __restrict__ bars){
  extern __shared__ char smem[];
  char* ldsA = smem;            // 65536
  char* bstE = smem + 65536;    // 16*592 = 9472
  int blk = blockIdx.x, tid = threadIdx.x;
  int us = blk & 7, bh = (blk>>3)&1, d = blk>>4;
  int dom = d*2 + bh;
  unsigned* ctr = bars + dom*16;
  int w = tid >> 6, l = tid & 63;
  int lr = l & 15, lk = l >> 4;
  { const uint4* s = (const uint4*)(encA + (size_t)(d*8+us)*32768);
    uint4* dst = (uint4*)ldsA;
    for (int i = tid; i < 4096; i += 256) dst[i] = s[i]; }
  { uint4* b4 = (uint4*)bstE;
    uint4 zz = make_uint4(0,0,0,0);
    for (int i = tid; i < 592; i += 256) b4[i] = zz; }
  float c0 = 0.f, c1 = 0.f;
  int b_g = bh*16 + lr;
  int u0 = (w*2+0)*4 + lk, u1_ = (w*2+1)*4 + lk;
  int uc0 = us*32 + u0, uc1 = us*32 + u1_;
  __syncthreads();
  for (int i = 0; i < 256; i++){
    int t = d ? (255 - i) : i;
    const float* zr = Z + ((size_t)t*32 + b_g)*2048 + d*1024;
    float za[4], zb[4];
    #pragma unroll
    for (int j = 0; j < 4; j++){ za[j] = zr[j*256 + uc0]; zb[j] = zr[j*256 + uc1]; }
    f32x4 acc0 = (f32x4){0.f,0.f,0.f,0.f};
    f32x4 acc1 = (f32x4){0.f,0.f,0.f,0.f};
    #pragma unroll
    for (int kk = 0; kk < 8; kk++){
      short8v bF = *(const short8v*)(bstE + lr*592 + kk*64 + lk*16);
      short8v a0 = *(const short8v*)(ldsA + (((w*2+0)*8 + kk)*64 + l)*16);
      short8v a1 = *(const short8v*)(ldsA + (((w*2+1)*8 + kk)*64 + l)*16);
      acc0 = __builtin_amdgcn_mfma_f32_16x16x32_bf16(a0, bF, acc0, 0, 0, 0);
      acc1 = __builtin_amdgcn_mfma_f32_16x16x32_bf16(a1, bF, acc1, 0, 0, 0);
    }
    float z0 = acc0[0]+za[0], z1 = acc0[1]+za[1], z2 = acc0[2]+za[2], z3 = acc0[3]+za[3];
    float cn = sigf(z1)*c0 + sigf(z0)*tanhf_fast(z2);
    float hn0 = sigf(z3)*tanhf_fast(cn); c0 = cn;
    z0 = acc1[0]+zb[0]; z1 = acc1[1]+zb[1]; z2 = acc1[2]+zb[2]; z3 = acc1[3]+zb[3];
    cn = sigf(z1)*c1 + sigf(z0)*tanhf_fast(z2);
    float hn1 = sigf(z3)*tanhf_fast(cn); c1 = cn;
    size_t yr = ((size_t)t*32 + b_g)*512 + d*256;
    y[yr + uc0] = hn0; y[yr + uc1] = hn1;
    float* hx = hexb + ((size_t)(dom*2 + (i&1)))*4096;
    ast(&hx[lr*256 + uc0], hn0);
    ast(&hx[lr*256 + uc1], hn1);
    if (i == 255){
      size_t fb = ((size_t)d*32 + b_g)*256;
      hfin[fb + uc0] = hn0; hfin[fb + uc1] = hn1;
      cfin[fb + uc0] = c0;  cfin[fb + uc1] = c1;
      break;
    }
    icbar(ctr, (unsigned)(i+1)*8u);
    {
      int bs = tid >> 4, seg = tid & 15;
      const float* srcp = hexb + ((size_t)(dom*2 + (i&1)))*4096 + bs*256 + seg*16;
      unsigned pk[8];
      #pragma unroll
      for (int s2 = 0; s2 < 8; s2++){
        float2 v = ald2(srcp + 2*s2);
        pk[s2] = (unsigned)f2bf(v.x) | ((unsigned)f2bf(v.y) << 16);
      }
      uint4* dsd = (uint4*)(bstE + bs*592 + seg*32);
      dsd[0] = make_uint4(pk[0],pk[1],pk[2],pk[3]);
      dsd[1] = make_uint4(pk[4],pk[5],pk[6],pk[7]);
    }
    __syncthreads();
  }
}

// ---------------- persistent MFMA decoder scan ----------------
// 256 blocks, single hierarchical domain. 4 phases/step. Fence-free barriers.
__global__ __launch_bounds__(256) void k_dec_scan(
    const float* __restrict__ aT, const float* __restrict__ eproj,
    const float* __restrict__ aW2, const float* __restrict__ y1,
    const float* __restrict__ zpre, const float* __restrict__ db1,
    const u16* __restrict__ decA,
    const float* __restrict__ e0c, const float* __restrict__ e1c,
    float* __restrict__ h0buf, float* __restrict__ h1buf,
    float* __restrict__ qbuf, float* __restrict__ ctxa,
    float* __restrict__ H1all, unsigned* __restrict__ bars){
  extern __shared__ char smem[];
  char* ldsA = smem;                 // 65536 (2 cells x 32KB)
  char* bst  = smem + 65536;         // 32*2128 = 68096
  float* scr = (float*)(smem + 133632); // 4608B
  int Bid = blockIdx.x, tid = threadIdx.x;
  int w = tid >> 6, l = tid & 63;
  int n_ = w & 1, kh = w >> 1;
  int lr = l & 15, lk = l >> 4;
  { const uint4* s = (const uint4*)(decA + (size_t)Bid*32768);
    uint4* d4 = (uint4*)ldsA;
    for (int i = tid; i < 4096; i += 256) d4[i] = s[i]; }
  int b_att = Bid >> 3, sub = Bid & 7;
  bool epi = (kh == 1) && (lk < 2);
  int u1 = lk & 1;
  int b_ep = n_*16 + lr;
  int ug = Bid*2 + u1;
  float c0r = 0.f, c1r = 0.f, d0 = 0.f, d1 = 0.f, d2 = 0.f, d3 = 0.f;
  if (epi){
    int dd = ug >> 8, uu = ug & 255;
    c0r = e0c[((size_t)dd*32 + b_ep)*256 + uu];
    c1r = e1c[((size_t)dd*32 + b_ep)*256 + uu];
    d0 = db1[0*512 + ug]; d1 = db1[1*512 + ug];
    d2 = db1[2*512 + ug]; d3 = db1[3*512 + ug];
  }
  __syncthreads();
  unsigned gen = 0;
  for (int t = 0; t < TD_; t++){
    int hp = t & 1, cp = t & 1;
    // ===== phase 1: q slice =====
    {
      float* h1s = scr; float* qred = scr + 512;
      float2 hv = ald2(&h1buf[(size_t)hp*16384 + b_att*512 + 2*tid]);
      h1s[2*tid] = hv.x; h1s[2*tid+1] = hv.y;
      if (tid < 64) ast(&ctxa[(size_t)(1-cp)*16640 + b_att*520 + sub*64 + tid], 0.f);
      if (sub == 0 && tid >= 64 && tid < 72)
        ast(&ctxa[(size_t)(1-cp)*16640 + b_att*520 + 448 + tid], 0.f);
      __syncthreads();
      int c32 = tid & 31, kc = tid >> 5;
      const float4* w4 = (const float4*)aT;
      const float4* h4 = (const float4*)h1s;
      float a = 0.f;
      #pragma unroll 4
      for (int jj = 0; jj < 16; jj++){
        int k4 = kc*16 + jj;
        float4 wv = w4[(size_t)k4*256 + sub*32 + c32];
        float4 hv2 = h4[k4];
        a += wv.x*hv2.x + wv.y*hv2.y + wv.z*hv2.z + wv.w*hv2.w;
      }
      qred[c32*9 + kc] = a;
      __syncthreads();
      if (tid < 32){
        float q = 0.f;
        #pragma unroll
        for (int k = 0; k < 8; k++) q += qred[tid*9 + k];
        ast(&qbuf[b_att*256 + sub*32 + tid], q);
      }
    }
    icbar2(bars, ++gen);
    // ===== phase 2: scores + exp + partial ctx =====
    {
      float* qs = scr; float* w2s = scr + 256; float* sred = scr + 512; float* esc = scr + 800;
      qs[tid] = ald(&qbuf[b_att*256 + tid]);
      w2s[tid] = aW2[tid];
      __syncthreads();
      int sl = tid >> 3, hc = tid & 7;
      int s = sub*32 + sl;
      const float4* ep = (const float4*)(eproj + ((size_t)s*32 + b_att)*256 + hc*32);
      const float4* q4 = (const float4*)(qs + hc*32);
      const float4* w24 = (const float4*)(w2s + hc*32);
      float acc = 0.f;
      #pragma unroll
      for (int k = 0; k < 8; k++){
        float4 e = ep[k], qq = q4[k], ww = w24[k];
        acc += tanhf_fast(e.x+qq.x)*ww.x + tanhf_fast(e.y+qq.y)*ww.y
             + tanhf_fast(e.z+qq.z)*ww.z + tanhf_fast(e.w+qq.w)*ww.w;
      }
      sred[sl*9 + hc] = acc;
      __syncthreads();
      if (hc == 0){
        float r = 0.f;
        #pragma unroll
        for (int k = 0; k < 8; k++) r += sred[sl*9 + k];
        esc[sl] = __expf(r);   // skip max & b2: softmax shift-invariant
      }
      __syncthreads();
      float a0 = 0.f, a1 = 0.f;
      #pragma unroll 4
      for (int s2 = 0; s2 < 32; s2++){
        float e = esc[s2];
        float2 v = *(const float2*)(y1 + ((size_t)(sub*32 + s2)*32 + b_att)*512 + tid*2);
        a0 += e*v.x; a1 += e*v.y;
      }
      __hip_atomic_fetch_add(&ctxa[(size_t)cp*16640 + b_att*520 + tid*2], a0,
                             __ATOMIC_RELAXED, __HIP_MEMORY_SCOPE_AGENT);
      __hip_atomic_fetch_add(&ctxa[(size_t)cp*16640 + b_att*520 + tid*2 + 1], a1,
                             __ATOMIC_RELAXED, __HIP_MEMORY_SCOPE_AGENT);
      if (tid == 0){
        float ss = 0.f;
        for (int k = 0; k < 32; k++) ss += esc[k];
        __hip_atomic_fetch_add(&ctxa[(size_t)cp*16640 + b_att*520 + 512], ss,
                               __ATOMIC_RELAXED, __HIP_MEMORY_SCOPE_AGENT);
      }
    }
    icbar2(bars, ++gen);
    // ===== phase 3: cell0 =====
    {
      int b_s = tid >> 3, pr = tid & 7;
      const float* A_ = ctxa + (size_t)cp*16640 + b_s*520;
      const float* B_ = h0buf + (size_t)hp*16384 + b_s*512;
      float sc_ = 1.0f / ald(A_ + 512);
      for (int i8 = 0; i8 < 16; i8++){
        int cch = i8*8 + pr;           // bank-spread chunk index
        unsigned pk[4];
        #pragma unroll
        for (int pj = 0; pj < 4; pj++){
          int p = cch*4 + pj;
          float2 v;
          if (p < 256){ v = ald2(A_ + 2*p); v.x *= sc_; v.y *= sc_; }
          else        { v = ald2(B_ + 2*p - 512); }
          pk[pj] = (unsigned)f2bf(v.x) | ((unsigned)f2bf(v.y) << 16);
        }
        *(uint4*)(bst + b_s*2128 + cch*16) = make_uint4(pk[0],pk[1],pk[2],pk[3]);
      }
      __syncthreads();
      f32x4 acc = (f32x4){0.f,0.f,0.f,0.f};
      #pragma unroll
      for (int kk = kh*16; kk < kh*16 + 16; kk++){
        short8v aF = *(const short8v*)(ldsA + (kk*64 + l)*16);
        short8v bF = *(const short8v*)(bst + (n_*16 + lr)*2128 + kk*64 + lk*16);
        acc = __builtin_amdgcn_mfma_f32_16x16x32_bf16(aF, bF, acc, 0, 0, 0);
      }
      float* zred = scr;
      if (kh == 0) *(f32x4*)&zred[(n_*64 + l)*4] = acc;
      __syncthreads();
      if (epi){
        f32x4 o = *(f32x4*)&zred[(n_*64 + l)*4];
        const float* zp = zpre + ((size_t)t*32 + b_ep)*2048 + ug;
        float z0 = acc[0]+o[0]+zp[0],    z1 = acc[1]+o[1]+zp[512];
        float z2 = acc[2]+o[2]+zp[1024], z3 = acc[3]+o[3]+zp[1536];
        float cn = sigf(z1)*c0r + sigf(z0)*tanhf_fast(z2);
        float hn = sigf(z3)*tanhf_fast(cn);
        c0r = cn;
        ast(&h0buf[(size_t)(1-hp)*16384 + b_ep*512 + ug], hn);
      }
    }
    icbar2(bars, ++gen);
    // ===== phase 4: cell1 =====
    {
      int b_s = tid >> 3, pr = tid & 7;
      const float* A_ = h0buf + (size_t)(1-hp)*16384 + b_s*512;
      const float* B_ = h1buf + (size_t)hp*16384 + b_s*512;
      for (int i8 = 0; i8 < 16; i8++){
        int cch = i8*8 + pr;
        unsigned pk[4];
        #pragma unroll
        for (int pj = 0; pj < 4; pj++){
          int p = cch*4 + pj;
          float2 v = (p < 256) ? ald2(A_ + 2*p) : ald2(B_ + 2*p - 512);
          pk[pj] = (unsigned)f2bf(v.x) | ((unsigned)f2bf(v.y) << 16);
        }
        *(uint4*)(bst + b_s*2128 + cch*16) = make_uint4(pk[0],pk[1],pk[2],pk[3]);
      }
      __syncthreads();
      f32x4 acc = (f32x4){0.f,0.f,0.f,0.f};
      #pragma unroll
      for (int kk = kh*16; kk < kh*16 + 16; kk++){
        short8v aF = *(const short8v*)(ldsA + 32768 + (kk*64 + l)*16);
        short8v bF = *(const short8v*)(bst + (n_*16 + lr)*2128 + kk*64 + lk*16);
        acc = __builtin_amdgcn_mfma_f32_16x16x32_bf16(aF, bF, acc, 0, 0, 0);
      }
      float* zred = scr;
      if (kh == 0) *(f32x4*)&zred[(n_*64 + l)*4] = acc;
      __syncthreads();
      if (epi){
        f32x4 o = *(f32x4*)&zred[(n_*64 + l)*4];
        float z0 = acc[0]+o[0]+d0, z1 = acc[1]+o[1]+d1;
        float z2 = acc[2]+o[2]+d2, z3 = acc[3]+o[3]+d3;
        float cn = sigf(z1)*c1r + sigf(z0)*tanhf_fast(z2);
        float hn = sigf(z3)*tanhf_fast(cn);
        c1r = cn;
        ast(&h1buf[(size_t)(1-hp)*16384 + b_ep*512 + ug], hn);
        H1all[((size_t)t*32 + b_ep)*512 + ug] = hn;
      }
    }
    if (t < TD_-1) icbar2(bars, ++gen);
  }
}

// decoder h-state init (parity 0)
__global__ void k_dinit(const float* __restrict__ eh0, const float* __restrict__ eh1,
                        float* __restrict__ h0b, float* __restrict__ h1b){
  int idx = blockIdx.x*256 + threadIdx.x;
  if (idx >= 16384) return;
  int b = idx >> 9, u = idx & 511, dd = u >> 8, uu = u & 255;
  h0b[idx] = eh0[(dd*32 + b)*256 + uu];
  h1b[idx] = eh1[(dd*32 + b)*256 + uu];
}

// ---------------- host launch ----------------
extern "C" void kernel_launch(void* const* d_in, const int* in_sizes, int n_in,
                              void* d_out, int out_size, void* d_ws, size_t ws_size,
                              hipStream_t stream){
  (void)in_sizes; (void)n_in; (void)out_size; (void)ws_size;
  const int*   src   = (const int*)d_in[0];
  const int*   tgt   = (const int*)d_in[1];
  const float* emb   = (const float*)d_in[2];
  const float* eWih0 = (const float*)d_in[3];
  const float* eWhh0 = (const float*)d_in[4];
  const float* eb0   = (const float*)d_in[5];
  const float* eWih1 = (const float*)d_in[6];
  const float* eWhh1 = (const float*)d_in[7];
  const float* eb1   = (const float*)d_in[8];
  const float* dWih0 = (const float*)d_in[9];
  const float* dWhh0 = (const float*)d_in[10];
  const float* db0   = (const float*)d_in[11];
  const float* dWih1 = (const float*)d_in[12];
  const float* dWhh1 = (const float*)d_in[13];
  const float* db1   = (const float*)d_in[14];
  const float* aW1   = (const float*)d_in[15];
  const float* ab1   = (const float*)d_in[16];
  const float* aW2   = (const float*)d_in[17];
  const float* oW1   = (const float*)d_in[19];
  const float* ob1   = (const float*)d_in[20];
  const float* oW2   = (const float*)d_in[21];
  const float* ob2   = (const float*)d_in[22];

  float* F = (float*)d_out;
  float* Z     = F + OFF_Z;
  float* y0    = F + OFF_Y0;
  float* y1    = F + OFF_Y1;
  float* zpre  = F + OFF_ZPRE;
  float* H1    = F + OFF_H1ALL;
  float* srcE  = F + OFF_SRCE;
  float* tgtE  = F + OFF_TGTE;
  float* eproj = F + OFF_EPROJ;
  u16*   encA0 = (u16*)(F + OFF_ENCA0);
  u16*   encA1 = (u16*)(F + OFF_ENCA1);
  u16*   decA  = (u16*)(F + OFF_DECA);
  float* aT    = F + OFF_AT;
  float* e0h   = F + OFF_E0H;
  float* e0c   = F + OFF_E0C;
  float* e1h   = F + OFF_E1H;
  float* e1c   = F + OFF_E1C;
  float* h0buf = F + OFF_H0BUF;
  float* h1buf = F + OFF_H1BUF;
  float* hexb  = F + OFF_HEX;
  float* qbuf  = F + OFF_QBUF;
  float* ctxa  = F + OFF_CTXA;
  unsigned* bars = (unsigned*)(F + OFF_BARS);
  float* hid   = (float*)d_ws;

  hipFuncSetAttribute((const void*)k_enc_scan, hipFuncAttributeMaxDynamicSharedMemorySize, 75008);
  hipFuncSetAttribute((const void*)k_dec_scan, hipFuncAttributeMaxDynamicSharedMemorySize, 138240);

  // zero ctx accumulators + barrier counters (contiguous)
  k_zero<<<(34304+255)/256,256,0,stream>>>(F + OFF_CTXA, 34304);
  k_gather<<<((8192+2016)*32+255)/256,256,0,stream>>>(src, tgt, emb, srcE, tgtE);
  k_prep_encA<<<2048,256,0,stream>>>(eWhh0, encA0);
  k_prep_encA<<<2048,256,0,stream>>>(eWhh1, encA1);
  k_prep_decA<<<32768,256,0,stream>>>(dWih0, dWhh0, dWih1, dWhh1, decA);
  k_transpose<<<dim3(4,8),256,0,stream>>>(aW1, aT, 256,512,1024,0);

  // encoder layer0
  k_mgemm<<<dim3(64,16),256,0,stream>>>(srcE, eWih0, eb0, Z, 8192,2048,128, 128,0,0);
  k_enc_scan<<<32,256,75008,stream>>>(Z, encA0, y0, hexb, e0h, e0c, bars);
  // encoder layer1
  k_mgemm<<<dim3(64,16),256,0,stream>>>(y0, eWih1, eb1, Z, 8192,2048,512, 512,0,0);
  k_enc_scan<<<32,256,75008,stream>>>(Z, encA1, y1, hexb, e1h, e1c, bars + 320);

  // projections
  k_mgemm<<<dim3(64,2),256,0,stream>>>(y1, aW1, ab1, eproj, 8192,256,512, 1024,512,0);
  k_mgemm<<<dim3(16,16),256,0,stream>>>(tgtE, dWih0, db0, zpre, 2016,2048,128, 640,0,0);
  k_dinit<<<64,256,0,stream>>>(e0h, e1h, h0buf, h1buf);

  // decoder
  k_dec_scan<<<256,256,138240,stream>>>(aT, eproj, aW2, y1, zpre, db1, decA,
                                        e0c, e1c, h0buf, h1buf, qbuf, ctxa, H1, bars + 640);

  // output head
  k_mgemm<<<dim3(16,2),256,0,stream>>>(H1, oW1, ob1, hid, 2016,256,512, 512,0,1);
  k_mgemm<<<dim3(16,250),256,0,stream>>>(hid, oW2, ob2, F, 2016,32000,256, 256,0,2);
}